// Round 14
// baseline (44.631 us; speedup 1.0000x reference)
//
#include <hip/hip_runtime.h>
#include <math.h>

constexpr int D  = 768;
constexpr int NQ = 8;
constexpr int B  = 32;
constexpr int NP = 196;      // n_patch
constexpr int KT = 7;        // K tiles of 32
constexpr int KP = KT * 32;  // 224 padded K
constexpr int TPAD = 776;    // LDS tile row stride (shorts)
constexpr int CS = 24;       // 32-col output slices
constexpr float EPS = 1e-5f;
constexpr float INV_SQRT_D = 0.036084391824351615f;  // 1/sqrt(768)

typedef __attribute__((ext_vector_type(8))) short short8;
typedef __attribute__((ext_vector_type(4))) float f32x4;

__device__ __forceinline__ float wave_reduce_sum(float v) {
#pragma unroll
    for (int off = 32; off > 0; off >>= 1) v += __shfl_xor(v, off, 64);
    return v;
}
__device__ __forceinline__ float wave_reduce_max(float v) {
#pragma unroll
    for (int off = 32; off > 0; off >>= 1) v = fmaxf(v, __shfl_xor(v, off, 64));
    return v;
}

__device__ __forceinline__ unsigned short f2bf(float x) {
    union { float f; unsigned u; } c; c.f = x;
    unsigned r = c.u + 0x7fffu + ((c.u >> 16) & 1u);   // RNE
    return (unsigned short)(r >> 16);
}

// Fused: LN(q)->qbf LDS + LN(kv 16-row half-tile) + MFMA scores S + frag pack.
// kvTf[b][dt:48][kt:7][slot:64][e:8], value = kvn[kt*32+kg*8+e][dt*16+dl].
// One block per (b, h), h in [0,14): rows [h*16, h*16+16).
__global__ __launch_bounds__(256, 4) void kv_fused(const float* __restrict__ q_x,
                                                   const float* __restrict__ qw,
                                                   const float* __restrict__ qb,
                                                   const float* __restrict__ kv_x,
                                                   const float* __restrict__ kw,
                                                   const float* __restrict__ kb,
                                                   float* __restrict__ S,
                                                   unsigned short* __restrict__ kvTf) {
    const int b = blockIdx.x / 14;
    const int h = blockIdx.x % 14;
    const int kt = h >> 1;
    const int kgbase = (h & 1) * 2;
    const int tid = threadIdx.x, wave = tid >> 6, lane = tid & 63;
    __shared__ unsigned short tile[16][TPAD];  // 24.8 KB
    __shared__ unsigned short qbf[8][TPAD];    // 12.4 KB

    const bool live = (h * 16) < NP;

    float wv[12], bv[12];
#pragma unroll
    for (int c = 0; c < 12; ++c) { wv[c] = kw[lane + 64 * c]; bv[c] = kb[lane + 64 * c]; }

    // q-LN -> qbf (bf16), distributed: wave w handles q rows {2w, 2w+1}
    if (live && wave < 4) {
        float wq[12], bq[12];
#pragma unroll
        for (int c = 0; c < 12; ++c) { wq[c] = qw[lane + 64 * c]; bq[c] = qb[lane + 64 * c]; }
        for (int rr = 0; rr < 2; ++rr) {
            const int q = wave * 2 + rr;
            float v[12];
            float s = 0.f;
#pragma unroll
            for (int c = 0; c < 12; ++c) { v[c] = q_x[q * D + lane + 64 * c]; s += v[c]; }
            s = wave_reduce_sum(s);
            const float mean = s * (1.0f / D);
            float ss = 0.f;
#pragma unroll
            for (int c = 0; c < 12; ++c) { v[c] -= mean; ss += v[c] * v[c]; }
            ss = wave_reduce_sum(ss);
            const float rs = rsqrtf(ss * (1.0f / D) + EPS);
#pragma unroll
            for (int c = 0; c < 12; ++c)
                qbf[q][lane + 64 * c] = f2bf(v[c] * rs * wq[c] + bq[c]);
        }
    }

    // kv-LN -> tile (bf16)
    for (int r = 0; r < 4; ++r) {
        const int nl = wave * 4 + r;
        const int n  = h * 16 + nl;
        if (n < NP) {
            const float* xr = kv_x + ((size_t)b * NP + n) * D;
            float v[12];
            float s = 0.f;
#pragma unroll
            for (int c = 0; c < 12; ++c) { v[c] = xr[lane + 64 * c]; s += v[c]; }
            s = wave_reduce_sum(s);
            const float mean = s * (1.0f / D);
            float ss = 0.f;
#pragma unroll
            for (int c = 0; c < 12; ++c) { v[c] -= mean; ss += v[c] * v[c]; }
            ss = wave_reduce_sum(ss);
            const float rs = rsqrtf(ss * (1.0f / D) + EPS);
#pragma unroll
            for (int c = 0; c < 12; ++c)
                tile[nl][lane + 64 * c] = f2bf(v[c] * rs * wv[c] + bv[c]);
        } else {
#pragma unroll
            for (int c = 0; c < 12; ++c) tile[nl][lane + 64 * c] = 0;
        }
    }
    __syncthreads();

    // frag-layout store: 48 dt * 32 local slots = 1536 chunks of 16B, 6/thread.
#pragma unroll
    for (int rep = 0; rep < 6; ++rep) {
        const int chunk = rep * 256 + tid;
        const int dt = chunk >> 5, ls = chunk & 31;
        const int hi = ls >> 4, dl = ls & 15;
        const int kg = kgbase + hi;
        short8 vals;
#pragma unroll
        for (int e = 0; e < 8; ++e)
            vals[e] = (short)tile[hi * 8 + e][dt * 16 + dl];
        *(short8*)(kvTf + ((((size_t)b * 48 + dt) * KT + kt) * 64 + kg * 16 + dl) * 8) = vals;
    }

    // scores via MFMA: S16x8 = tile(16 x 768) x qbf^T, wave 0 only.
    // B-col q: cols 8-15 alias 0-7 (discarded). C: col=lane&15, row=(lane>>4)*4+reg.
    if (live && wave == 0) {
        f32x4 s0 = {0.f, 0.f, 0.f, 0.f}, s1 = {0.f, 0.f, 0.f, 0.f};
        const int ar = lane & 15, akg = lane >> 4;
        const int qr = ar & 7;
#pragma unroll
        for (int k2 = 0; k2 < 24; k2 += 2) {
            s0 = __builtin_amdgcn_mfma_f32_16x16x32_bf16(
                *(const short8*)&tile[ar][k2 * 32 + akg * 8],
                *(const short8*)&qbf[qr][k2 * 32 + akg * 8], s0, 0, 0, 0);
            s1 = __builtin_amdgcn_mfma_f32_16x16x32_bf16(
                *(const short8*)&tile[ar][(k2 + 1) * 32 + akg * 8],
                *(const short8*)&qbf[qr][(k2 + 1) * 32 + akg * 8], s1, 0, 0, 0);
        }
        s0 = s0 + s1;
        const int q = lane & 15;
        if (q < NQ) {
#pragma unroll
            for (int reg = 0; reg < 4; ++reg) {
                const int n = h * 16 + akg * 4 + reg;
                if (n < NP) S[((size_t)b * NQ + q) * NP + n] = s0[reg] * INV_SQRT_D;
            }
        }
    }
}

// Softmax once per unordered pair u={i<j}: 16 rows r = dir*8+q
// (dir0 = softmax(S_i - S_j), dir1 = softmax(S_j - S_i)), written bf16 in
// MFMA-frag layout Abf[u][kt:7][slot:64][e:8], slot = kg*16 + r.
__global__ __launch_bounds__(512) void aprep(const float* __restrict__ S,
                                             unsigned short* __restrict__ Abf) {
    const int u = blockIdx.x;
    int uu = u, i = 0;
    while (uu >= 31 - i) { uu -= 31 - i; ++i; }
    const int j = i + 1 + uu;

    const int tid = threadIdx.x, wave = tid >> 6, lane = tid & 63;
    __shared__ unsigned short lrow[16][KP];  // 7 KB

    for (int jj = 0; jj < 2; ++jj) {
        const int r = wave * 2 + jj;          // 0..15
        const int dir = r >> 3, q = r & 7;
        const float* Sa = S + ((size_t)(dir ? j : i) * NQ + q) * NP;
        const float* Sb = S + ((size_t)(dir ? i : j) * NQ + q) * NP;
        float v[4];
        float m = -1e30f;
#pragma unroll
        for (int c = 0; c < 4; ++c) {
            const int n = lane + 64 * c;
            v[c] = (n < NP) ? (Sa[n] - Sb[n]) : -1e30f;
            m = fmaxf(m, v[c]);
        }
        m = wave_reduce_max(m);
        float e[4];
        float sum = 0.f;
#pragma unroll
        for (int c = 0; c < 4; ++c) {
            const int n = lane + 64 * c;
            e[c] = (n < NP) ? __expf(v[c] - m) : 0.f;
            sum += e[c];
        }
        sum = wave_reduce_sum(sum);
        const float rinv = 1.0f / sum;
#pragma unroll
        for (int c = 0; c < 4; ++c) {
            const int n = lane + 64 * c;
            if (n < KP) lrow[r][n] = (n < NP) ? f2bf(e[c] * rinv) : (unsigned short)0;
        }
    }
    __syncthreads();

    if (tid < 448) {
        const int kt = tid >> 6, slot = tid & 63;
        const int kg = slot >> 4, lr = slot & 15;
        const short8 vals = *(const short8*)(&lrow[lr][kt * 32 + kg * 8]);
        *(short8*)(Abf + (((size_t)u * KT + kt) * 64 + slot) * 8) = vals;
    }
}

// dgemm v3: quad-wave LDS-staged pair GEMM, 256 thr (4 waves), 48 KB LDS.
// Block = (bt, cs): cs in [0,24) = 32-col slice (2 dt).
//  bt < 12: full 8x8 group-rect (gA<gB), j-half jh: 8 i-panels + 4 j-panels.
//  bt >= 12: diagonal 8-triangle g8, j-half jh: 8 local panels.
// Wave = {i0,i1} x {j0..j3} x 2 dt: 8 pairs, 12 ds_reads per 32 MFMAs.
// acc[p] = A_p @ kv_i + A_p @ (-kv_j); store dir0 -> out[i*B+j], dir1 -> -acc.
// Triangle jh=0 waves 2,3 are fully masked -> zero-fill diagonal outputs.
__global__ __launch_bounds__(256) void dgemm(const unsigned short* __restrict__ Abf,
                                             const unsigned short* __restrict__ kvTf,
                                             float* __restrict__ out) {
    const int bid = blockIdx.x;
    const int cs = bid % CS, bt = bid / CS;   // XCD = bid%8 = cs%8
    const int tid = threadIdx.x, wave = tid >> 6, lane = tid & 63;

    __shared__ unsigned short stg[2][12][2][64][8];  // 48 KB

    const bool rect = bt < 12;
    int ib0, jb0, jpanb, g8 = 0, jh = 0;
    if (rect) {
        const int ft = bt >> 1;
        jh = bt & 1;
        const int gA = (ft < 3) ? 0 : ((ft < 5) ? 1 : 2);
        const int gB = (ft < 3) ? (ft + 1) : ((ft < 5) ? (ft - 1) : 3);
        ib0 = 8 * gA; jb0 = 8 * gB + 4 * jh; jpanb = 8;
    } else {
        g8 = (bt - 12) >> 1; jh = (bt - 12) & 1;
        ib0 = 8 * g8; jb0 = 8 * g8 + 4 * jh; jpanb = 4 * jh;
    }

    // ---- pair decode: 8 pairs = {i0,i1} x {j0..j3} ----
    int ig[2], jg[4];
    ig[0] = ib0 + 2 * wave; ig[1] = ig[0] + 1;
#pragma unroll
    for (int jj = 0; jj < 4; ++jj) jg[jj] = jb0 + jj;
    bool valid[8];
    bool any = false;
#pragma unroll
    for (int p = 0; p < 8; ++p) {
        valid[p] = ig[p >> 2] < jg[p & 3];
        any = any || valid[p];
    }
    const bool compute = any;

    // zero-fill diagonal outputs (triangle jh==0, waves 2,3: 4 outputs each)
    if (!rect && jh == 0 && wave >= 2) {
#pragma unroll
        for (int t2 = 0; t2 < 4; ++t2) {
            const int ii = ib0 + (wave - 2) * 4 + t2;
            float* base = out + (size_t)(ii * B + ii) * NQ * D + cs * 32;
            const int col = lane & 31, qh = lane >> 5;
#pragma unroll
            for (int rr = 0; rr < 4; ++rr)
                base[(qh * 4 + rr) * D + col] = 0.f;
        }
    }

    // ---- A pointers (masked pairs -> safe dummy u=0) ----
    const unsigned short* Ap[8];
#pragma unroll
    for (int p = 0; p < 8; ++p) {
        const int i = ig[p >> 2], j = jg[p & 3];
        const int u = valid[p] ? (i * (63 - i)) / 2 + (j - i - 1) : 0;
        Ap[p] = Abf + (size_t)u * KT * 512 + (size_t)lane * 8;
    }

    short8 acur[8], anxt[8];
    if (compute) {
#pragma unroll
        for (int p = 0; p < 8; ++p) acur[p] = *(const short8*)(Ap[p]);
    }

    // ---- staging: rect 24 units (6/wave), tri 16 units (4/wave) ----
    // unit = p*2+dt; panel p -> global b.
    const int nst = rect ? 6 : 4;
    int sb[6], sdt[6], spn[6];
#pragma unroll
    for (int s = 0; s < 6; ++s) {
        const int unit = wave * nst + s;
        const int p = unit >> 1, dt = unit & 1;
        spn[s] = p; sdt[s] = dt;
        sb[s] = rect ? ((p < 8) ? (ib0 + p) : (jb0 + (p - 8))) : (ib0 + p);
    }

    f32x4 acc[8][2];
#pragma unroll
    for (int p = 0; p < 8; ++p)
#pragma unroll
        for (int dt = 0; dt < 2; ++dt) {
            f32x4 z = {0.f, 0.f, 0.f, 0.f};
            acc[p][dt] = z;
        }

    // prologue: stage kt=0
    for (int s = 0; s < nst; ++s)
        __builtin_amdgcn_global_load_lds(
            (const __attribute__((address_space(1))) void*)(
                kvTf + (((size_t)sb[s] * 48 + cs * 2 + sdt[s]) * KT) * 512 + (size_t)lane * 8),
            (__attribute__((address_space(3))) void*)(&stg[0][spn[s]][sdt[s]][0][0]), 16, 0, 0);
    __syncthreads();

    int buf = 0;
    for (int kt = 0; kt < KT; ++kt) {
        if (kt + 1 < KT) {
            for (int s = 0; s < nst; ++s)
                __builtin_amdgcn_global_load_lds(
                    (const __attribute__((address_space(1))) void*)(
                        kvTf + (((size_t)sb[s] * 48 + cs * 2 + sdt[s]) * KT + kt + 1) * 512 + (size_t)lane * 8),
                    (__attribute__((address_space(3))) void*)(&stg[buf ^ 1][spn[s]][sdt[s]][0][0]), 16, 0, 0);
            if (compute) {
#pragma unroll
                for (int p = 0; p < 8; ++p) anxt[p] = *(const short8*)(Ap[p] + (size_t)(kt + 1) * 512);
            }
        }
        if (compute) {
            const int il0 = 2 * wave;
#pragma unroll
            for (int dt = 0; dt < 2; ++dt) {
                const short8 ki0 = *(const short8*)(&stg[buf][il0][dt][lane][0]);
                const short8 ki1 = *(const short8*)(&stg[buf][il0 + 1][dt][lane][0]);
                short8 nkj[4];
#pragma unroll
                for (int jj = 0; jj < 4; ++jj) {
                    const short8 kj = *(const short8*)(&stg[buf][jpanb + jj][dt][lane][0]);
#pragma unroll
                    for (int e = 0; e < 8; ++e) nkj[jj][e] = (short)(kj[e] ^ (short)0x8000);
                }
#pragma unroll
                for (int ii2 = 0; ii2 < 2; ++ii2)
#pragma unroll
                    for (int jj = 0; jj < 4; ++jj) {
                        const int p = ii2 * 4 + jj;
                        acc[p][dt] = __builtin_amdgcn_mfma_f32_16x16x32_bf16(
                            acur[p], ii2 ? ki1 : ki0, acc[p][dt], 0, 0, 0);
                        acc[p][dt] = __builtin_amdgcn_mfma_f32_16x16x32_bf16(
                            acur[p], nkj[jj], acc[p][dt], 0, 0, 0);
                    }
            }
        }
        __syncthreads();
        if (compute && kt + 1 < KT) {
#pragma unroll
            for (int p = 0; p < 8; ++p) acur[p] = anxt[p];
        }
        buf ^= 1;
    }

    // ---- epilogue: C row-in-tile = (lane>>4)*4 + reg, col = lane&15 ----
    if (compute) {
        const int kgrp = lane >> 4, dl = lane & 15;
#pragma unroll
        for (int p = 0; p < 8; ++p) {
            if (valid[p]) {
                const int i = ig[p >> 2], j = jg[p & 3];
                const int pij = i * B + j, pji = j * B + i;
#pragma unroll
                for (int reg = 0; reg < 4; ++reg) {
                    const int r = kgrp * 4 + reg;
                    const int dirr = r >> 3, qq = r & 7;
                    const int po = dirr ? pji : pij;
                    const float sgn = dirr ? -1.f : 1.f;
                    float* op = out + ((size_t)po * NQ + qq) * D + cs * 32 + dl;
                    op[0]  = sgn * acc[p][0][reg];
                    op[16] = sgn * acc[p][1][reg];
                }
            }
        }
    }
}

extern "C" void kernel_launch(void* const* d_in, const int* in_sizes, int n_in,
                              void* d_out, int out_size, void* d_ws, size_t ws_size,
                              hipStream_t stream) {
    const float* q_x     = (const float*)d_in[0];
    const float* kv_x    = (const float*)d_in[1];
    const float* ln_q_w  = (const float*)d_in[2];
    const float* ln_q_b  = (const float*)d_in[3];
    const float* ln_kv_w = (const float*)d_in[4];
    const float* ln_kv_b = (const float*)d_in[5];
    float* out = (float*)d_out;

    float* ws = (float*)d_ws;
    float* S  = ws;                                             // 32*8*196 f32
    unsigned short* kvTf = (unsigned short*)(ws + B * NQ * NP);  // 32*48*7*512 bf16
    unsigned short* Abf  = kvTf + (size_t)B * 48 * KT * 512;     // 496*7*512 bf16

    kv_fused<<<B * 14, 256, 0, stream>>>(q_x, ln_q_w, ln_q_b, kv_x, ln_kv_w, ln_kv_b, S, kvTf);
    aprep<<<(B * (B - 1)) / 2, 512, 0, stream>>>(S, Abf);
    dgemm<<<20 * CS, 256, 0, stream>>>(Abf, kvTf, out);
}

// Round 15
// 38.873 us; speedup vs baseline: 1.1481x; 1.1481x over previous
//
#include <hip/hip_runtime.h>
#include <math.h>

constexpr int D  = 768;
constexpr int NQ = 8;
constexpr int B  = 32;
constexpr int NP = 196;      // n_patch
constexpr int KT = 7;        // K tiles of 32
constexpr int KP = KT * 32;  // 224 padded K
constexpr int TPAD = 776;    // LDS tile row stride (shorts)
constexpr int NTOFF = 28;    // off-diag 4x4-group tiles: C(8,2)
constexpr int NTILES = 32;   // + 4 diag-combo tiles (2 groups each)
constexpr float EPS = 1e-5f;
constexpr float INV_SQRT_D = 0.036084391824351615f;  // 1/sqrt(768)

typedef __attribute__((ext_vector_type(8))) short short8;
typedef __attribute__((ext_vector_type(4))) float f32x4;

__device__ __forceinline__ float wave_reduce_sum(float v) {
#pragma unroll
    for (int off = 32; off > 0; off >>= 1) v += __shfl_xor(v, off, 64);
    return v;
}
__device__ __forceinline__ float wave_reduce_max(float v) {
#pragma unroll
    for (int off = 32; off > 0; off >>= 1) v = fmaxf(v, __shfl_xor(v, off, 64));
    return v;
}

__device__ __forceinline__ unsigned short f2bf(float x) {
    union { float f; unsigned u; } c; c.f = x;
    unsigned r = c.u + 0x7fffu + ((c.u >> 16) & 1u);   // RNE
    return (unsigned short)(r >> 16);
}

// Fused: LN(q)->qbf LDS + LN(kv 16-row half-tile) + MFMA scores S + frag pack.
// kvTf[b][dt:48][kt:7][slot:64][e:8], value = kvn[kt*32+kg*8+e][dt*16+dl].
// One block per (b, h), h in [0,14): rows [h*16, h*16+16).
__global__ __launch_bounds__(256, 4) void kv_fused(const float* __restrict__ q_x,
                                                   const float* __restrict__ qw,
                                                   const float* __restrict__ qb,
                                                   const float* __restrict__ kv_x,
                                                   const float* __restrict__ kw,
                                                   const float* __restrict__ kb,
                                                   float* __restrict__ S,
                                                   unsigned short* __restrict__ kvTf) {
    const int b = blockIdx.x / 14;
    const int h = blockIdx.x % 14;
    const int kt = h >> 1;
    const int kgbase = (h & 1) * 2;
    const int tid = threadIdx.x, wave = tid >> 6, lane = tid & 63;
    __shared__ unsigned short tile[16][TPAD];  // 24.8 KB
    __shared__ unsigned short qbf[8][TPAD];    // 12.4 KB

    const bool live = (h * 16) < NP;

    float wv[12], bv[12];
#pragma unroll
    for (int c = 0; c < 12; ++c) { wv[c] = kw[lane + 64 * c]; bv[c] = kb[lane + 64 * c]; }

    // q-LN -> qbf (bf16), distributed: wave w handles q rows {2w, 2w+1}
    if (live && wave < 4) {
        float wq[12], bq[12];
#pragma unroll
        for (int c = 0; c < 12; ++c) { wq[c] = qw[lane + 64 * c]; bq[c] = qb[lane + 64 * c]; }
        for (int rr = 0; rr < 2; ++rr) {
            const int q = wave * 2 + rr;
            float v[12];
            float s = 0.f;
#pragma unroll
            for (int c = 0; c < 12; ++c) { v[c] = q_x[q * D + lane + 64 * c]; s += v[c]; }
            s = wave_reduce_sum(s);
            const float mean = s * (1.0f / D);
            float ss = 0.f;
#pragma unroll
            for (int c = 0; c < 12; ++c) { v[c] -= mean; ss += v[c] * v[c]; }
            ss = wave_reduce_sum(ss);
            const float rs = rsqrtf(ss * (1.0f / D) + EPS);
#pragma unroll
            for (int c = 0; c < 12; ++c)
                qbf[q][lane + 64 * c] = f2bf(v[c] * rs * wq[c] + bq[c]);
        }
    }

    // kv-LN -> tile (bf16)
    for (int r = 0; r < 4; ++r) {
        const int nl = wave * 4 + r;
        const int n  = h * 16 + nl;
        if (n < NP) {
            const float* xr = kv_x + ((size_t)b * NP + n) * D;
            float v[12];
            float s = 0.f;
#pragma unroll
            for (int c = 0; c < 12; ++c) { v[c] = xr[lane + 64 * c]; s += v[c]; }
            s = wave_reduce_sum(s);
            const float mean = s * (1.0f / D);
            float ss = 0.f;
#pragma unroll
            for (int c = 0; c < 12; ++c) { v[c] -= mean; ss += v[c] * v[c]; }
            ss = wave_reduce_sum(ss);
            const float rs = rsqrtf(ss * (1.0f / D) + EPS);
#pragma unroll
            for (int c = 0; c < 12; ++c)
                tile[nl][lane + 64 * c] = f2bf(v[c] * rs * wv[c] + bv[c]);
        } else {
#pragma unroll
            for (int c = 0; c < 12; ++c) tile[nl][lane + 64 * c] = 0;
        }
    }
    __syncthreads();

    // frag-layout store: 48 dt * 32 local slots = 1536 chunks of 16B, 6/thread.
#pragma unroll
    for (int rep = 0; rep < 6; ++rep) {
        const int chunk = rep * 256 + tid;
        const int dt = chunk >> 5, ls = chunk & 31;
        const int hi = ls >> 4, dl = ls & 15;
        const int kg = kgbase + hi;
        short8 vals;
#pragma unroll
        for (int e = 0; e < 8; ++e)
            vals[e] = (short)tile[hi * 8 + e][dt * 16 + dl];
        *(short8*)(kvTf + ((((size_t)b * 48 + dt) * KT + kt) * 64 + kg * 16 + dl) * 8) = vals;
    }

    // scores via MFMA: S16x8 = tile(16 x 768) x qbf^T, wave 0 only.
    // B-col q: cols 8-15 alias 0-7 (discarded). C: col=lane&15, row=(lane>>4)*4+reg.
    if (live && wave == 0) {
        f32x4 s0 = {0.f, 0.f, 0.f, 0.f}, s1 = {0.f, 0.f, 0.f, 0.f};
        const int ar = lane & 15, akg = lane >> 4;
        const int qr = ar & 7;
#pragma unroll
        for (int k2 = 0; k2 < 24; k2 += 2) {
            s0 = __builtin_amdgcn_mfma_f32_16x16x32_bf16(
                *(const short8*)&tile[ar][k2 * 32 + akg * 8],
                *(const short8*)&qbf[qr][k2 * 32 + akg * 8], s0, 0, 0, 0);
            s1 = __builtin_amdgcn_mfma_f32_16x16x32_bf16(
                *(const short8*)&tile[ar][(k2 + 1) * 32 + akg * 8],
                *(const short8*)&qbf[qr][(k2 + 1) * 32 + akg * 8], s1, 0, 0, 0);
        }
        s0 = s0 + s1;
        const int q = lane & 15;
        if (q < NQ) {
#pragma unroll
            for (int reg = 0; reg < 4; ++reg) {
                const int n = h * 16 + akg * 4 + reg;
                if (n < NP) S[((size_t)b * NQ + q) * NP + n] = s0[reg] * INV_SQRT_D;
            }
        }
    }
}

// Softmax once per unordered pair u={i<j}: 16 rows r = dir*8+q
// (dir0 = softmax(S_i - S_j), dir1 = softmax(S_j - S_i)), written bf16 in
// MFMA-frag layout Abf[u][kt:7][slot:64][e:8], slot = kg*16 + r.
__global__ __launch_bounds__(512) void aprep(const float* __restrict__ S,
                                             unsigned short* __restrict__ Abf) {
    const int u = blockIdx.x;
    int uu = u, i = 0;
    while (uu >= 31 - i) { uu -= 31 - i; ++i; }
    const int j = i + 1 + uu;

    const int tid = threadIdx.x, wave = tid >> 6, lane = tid & 63;
    __shared__ unsigned short lrow[16][KP];  // 7 KB

    for (int jj = 0; jj < 2; ++jj) {
        const int r = wave * 2 + jj;          // 0..15
        const int dir = r >> 3, q = r & 7;
        const float* Sa = S + ((size_t)(dir ? j : i) * NQ + q) * NP;
        const float* Sb = S + ((size_t)(dir ? i : j) * NQ + q) * NP;
        float v[4];
        float m = -1e30f;
#pragma unroll
        for (int c = 0; c < 4; ++c) {
            const int n = lane + 64 * c;
            v[c] = (n < NP) ? (Sa[n] - Sb[n]) : -1e30f;
            m = fmaxf(m, v[c]);
        }
        m = wave_reduce_max(m);
        float e[4];
        float sum = 0.f;
#pragma unroll
        for (int c = 0; c < 4; ++c) {
            const int n = lane + 64 * c;
            e[c] = (n < NP) ? __expf(v[c] - m) : 0.f;
            sum += e[c];
        }
        sum = wave_reduce_sum(sum);
        const float rinv = 1.0f / sum;
#pragma unroll
        for (int c = 0; c < 4; ++c) {
            const int n = lane + 64 * c;
            if (n < KP) lrow[r][n] = (n < NP) ? f2bf(e[c] * rinv) : (unsigned short)0;
        }
    }
    __syncthreads();

    if (tid < 448) {
        const int kt = tid >> 6, slot = tid & 63;
        const int kg = slot >> 4, lr = slot & 15;
        const short8 vals = *(const short8*)(&lrow[lr][kt * 32 + kg * 8]);
        *(short8*)(Abf + (((size_t)u * KT + kt) * 64 + slot) * 8) = vals;
    }
}

// LDS-staged pair GEMM, double-buffered global_load_lds, 2 pairs/wave.
// Block = (tile t, cs of 8): 96-col slice. 16 waves.
//  t < 28 (off-diag, groups gi<gj): wave = (pi, bh, dth): pairs
//    (i=4gi+pi, j=4gj+2bh) and (i, j+1), dt half = dth*3. Shared ki read.
//  t >= 28 (diag-combo): waves 0-11: ps=w>>1 picks 2 pairs from the 6-enum
//    of group g=ps/3; waves 12-15 zero-fill the 8 diagonal outputs.
// acc = A@kv_i + (-A)@kv_j; rows dir0 -> out[i*B+j], dir1 -> -acc at [j*B+i].
__global__ __launch_bounds__(1024) void dgemm(const unsigned short* __restrict__ Abf,
                                              const unsigned short* __restrict__ kvTf,
                                              float* __restrict__ out) {
    const int bid = blockIdx.x;
    const int t = bid >> 3, cs = bid & 7;
    const int tid = threadIdx.x, wave = tid >> 6, lane = tid & 63;

    __shared__ unsigned short stg[2][8][6][64][8];  // 96 KB double-buffered

    const bool offd = (t < NTOFF);
    int gi = 0, gj = 0;
    if (offd) {
        int tt = t, a = 0;
        while (tt >= 7 - a) { tt -= 7 - a; ++a; }
        gi = a; gj = a + 1 + tt;
    }
    const int dbase = 8 * (t - NTOFF);

    // ---- wave decode: 2 pairs + dt-half ----
    int i0 = 0, j0 = 0, i1 = 0, j1 = 0;
    int p0i = 0, p0j = 0, p1i = 0, p1j = 0, dth = 0;
    bool compute = true;
    if (offd) {
        const int pi = wave >> 2, bh = (wave >> 1) & 1;
        dth = wave & 1;
        i0 = 4 * gi + pi; j0 = 4 * gj + 2 * bh;
        i1 = i0;          j1 = j0 + 1;
        p0i = pi; p0j = 4 + 2 * bh; p1i = pi; p1j = p0j + 1;
    } else if (wave < 12) {
        const int ps = wave >> 1;
        dth = wave & 1;
        const int g = ps / 3, k3 = ps - 3 * g;
        const int ea[6] = {0, 0, 0, 1, 1, 2}, eb[6] = {1, 2, 3, 2, 3, 3};
        const int e0 = 2 * k3, e1 = e0 + 1;
        p0i = 4 * g + ea[e0]; p0j = 4 * g + eb[e0];
        p1i = 4 * g + ea[e1]; p1j = 4 * g + eb[e1];
        i0 = dbase + p0i; j0 = dbase + p0j;
        i1 = dbase + p1i; j1 = dbase + p1j;
    } else {
        compute = false;
        const int zw = wave - 12;
#pragma unroll
        for (int t2 = 0; t2 < 2; ++t2) {
            const int ii = dbase + zw * 2 + t2;
            float* base = out + (size_t)(ii * B + ii) * NQ * D + cs * 96;
            for (int e = lane; e < NQ * 96; e += 64) {
                const int q = e / 96, c = e - q * 96;
                base[q * D + c] = 0.f;
            }
        }
    }

    // ---- A prefetch to registers (2 pairs x 7 KB) ----
    short8 areg0[KT], areg1[KT];
    if (compute) {
        const int u0 = (i0 * (63 - i0)) / 2 + (j0 - i0 - 1);
        const int u1 = (i1 * (63 - i1)) / 2 + (j1 - i1 - 1);
        const unsigned short* Au0 = Abf + (size_t)u0 * KT * 512 + (size_t)lane * 8;
        const unsigned short* Au1 = Abf + (size_t)u1 * KT * 512 + (size_t)lane * 8;
#pragma unroll
        for (int kt = 0; kt < KT; ++kt) {
            areg0[kt] = *(const short8*)(Au0 + (size_t)kt * 512);
            areg1[kt] = *(const short8*)(Au1 + (size_t)kt * 512);
        }
    }

    // ---- staging: wave stages panel sp = wave>>1, dt [sd0,sd0+3) ----
    const int sp = wave >> 1;
    const int sd0 = (wave & 1) * 3;
    const int sb = offd ? ((sp < 4) ? (4 * gi + sp) : (4 * gj + sp - 4)) : (dbase + sp);
    const unsigned short* gbase =
        kvTf + (((size_t)sb * 48 + cs * 6 + sd0) * KT) * 512 + (size_t)lane * 8;

    f32x4 acc0[3], acc1[3];
#pragma unroll
    for (int nf = 0; nf < 3; ++nf) {
        f32x4 z = {0.f, 0.f, 0.f, 0.f};
        acc0[nf] = z; acc1[nf] = z;
    }

#pragma unroll
    for (int r = 0; r < 3; ++r)
        __builtin_amdgcn_global_load_lds(
            (const __attribute__((address_space(1))) void*)(gbase + ((size_t)r * KT) * 512),
            (__attribute__((address_space(3))) void*)(&stg[0][sp][sd0 + r][0][0]), 16, 0, 0);
    __syncthreads();

    int buf = 0;
    for (int kt = 0; kt < KT; ++kt) {
        if (kt + 1 < KT) {
#pragma unroll
            for (int r = 0; r < 3; ++r)
                __builtin_amdgcn_global_load_lds(
                    (const __attribute__((address_space(1))) void*)(gbase + ((size_t)r * KT + kt + 1) * 512),
                    (__attribute__((address_space(3))) void*)(&stg[buf ^ 1][sp][sd0 + r][0][0]), 16, 0, 0);
        }
        if (compute) {
            const short8 a0 = areg0[kt], a1 = areg1[kt];
            short8 na0, na1;
#pragma unroll
            for (int e = 0; e < 8; ++e) {
                na0[e] = (short)(a0[e] ^ (short)0x8000);
                na1[e] = (short)(a1[e] ^ (short)0x8000);
            }
            if (offd) {  // shared ki: 9 ds_reads feed 12 MFMAs
#pragma unroll
                for (int nf = 0; nf < 3; ++nf) {
                    const short8 ki  = *(const short8*)(&stg[buf][p0i][dth * 3 + nf][lane][0]);
                    const short8 kj0 = *(const short8*)(&stg[buf][p0j][dth * 3 + nf][lane][0]);
                    const short8 kj1 = *(const short8*)(&stg[buf][p1j][dth * 3 + nf][lane][0]);
                    acc0[nf] = __builtin_amdgcn_mfma_f32_16x16x32_bf16(a0,  ki,  acc0[nf], 0, 0, 0);
                    acc0[nf] = __builtin_amdgcn_mfma_f32_16x16x32_bf16(na0, kj0, acc0[nf], 0, 0, 0);
                    acc1[nf] = __builtin_amdgcn_mfma_f32_16x16x32_bf16(a1,  ki,  acc1[nf], 0, 0, 0);
                    acc1[nf] = __builtin_amdgcn_mfma_f32_16x16x32_bf16(na1, kj1, acc1[nf], 0, 0, 0);
                }
            } else {
#pragma unroll
                for (int nf = 0; nf < 3; ++nf) {
                    const short8 k0i = *(const short8*)(&stg[buf][p0i][dth * 3 + nf][lane][0]);
                    const short8 k0j = *(const short8*)(&stg[buf][p0j][dth * 3 + nf][lane][0]);
                    const short8 k1i = *(const short8*)(&stg[buf][p1i][dth * 3 + nf][lane][0]);
                    const short8 k1j = *(const short8*)(&stg[buf][p1j][dth * 3 + nf][lane][0]);
                    acc0[nf] = __builtin_amdgcn_mfma_f32_16x16x32_bf16(a0,  k0i, acc0[nf], 0, 0, 0);
                    acc0[nf] = __builtin_amdgcn_mfma_f32_16x16x32_bf16(na0, k0j, acc0[nf], 0, 0, 0);
                    acc1[nf] = __builtin_amdgcn_mfma_f32_16x16x32_bf16(a1,  k1i, acc1[nf], 0, 0, 0);
                    acc1[nf] = __builtin_amdgcn_mfma_f32_16x16x32_bf16(na1, k1j, acc1[nf], 0, 0, 0);
                }
            }
        }
        __syncthreads();
        buf ^= 1;
    }

    // ---- epilogue: C row-in-tile = (lane>>4)*4 + reg, col = lane&15 ----
    if (compute) {
        const int kgrp = lane >> 4, dl = lane & 15;
        const int colb = cs * 96 + dth * 48 + dl;
#pragma unroll
        for (int pr = 0; pr < 2; ++pr) {
            const int i = pr ? i1 : i0, j = pr ? j1 : j0;
            const f32x4* acc = pr ? acc1 : acc0;
            const int pij = i * B + j, pji = j * B + i;
#pragma unroll
            for (int reg = 0; reg < 4; ++reg) {
                const int r = kgrp * 4 + reg;
                const int dirr = r >> 3, qq = r & 7;
                const int p = dirr ? pji : pij;
                const float sgn = dirr ? -1.f : 1.f;
                float* op = out + ((size_t)p * NQ + qq) * D + colb;
#pragma unroll
                for (int nf = 0; nf < 3; ++nf) op[nf * 16] = sgn * acc[nf][reg];
            }
        }
    }
}

extern "C" void kernel_launch(void* const* d_in, const int* in_sizes, int n_in,
                              void* d_out, int out_size, void* d_ws, size_t ws_size,
                              hipStream_t stream) {
    const float* q_x     = (const float*)d_in[0];
    const float* kv_x    = (const float*)d_in[1];
    const float* ln_q_w  = (const float*)d_in[2];
    const float* ln_q_b  = (const float*)d_in[3];
    const float* ln_kv_w = (const float*)d_in[4];
    const float* ln_kv_b = (const float*)d_in[5];
    float* out = (float*)d_out;

    float* ws = (float*)d_ws;
    float* S  = ws;                                             // 32*8*196 f32
    unsigned short* kvTf = (unsigned short*)(ws + B * NQ * NP);  // 32*48*7*512 bf16
    unsigned short* Abf  = kvTf + (size_t)B * 48 * KT * 512;     // 496*7*512 bf16

    kv_fused<<<B * 14, 256, 0, stream>>>(q_x, ln_q_w, ln_q_b, kv_x, ln_kv_w, ln_kv_b, S, kvTf);
    aprep<<<(B * (B - 1)) / 2, 512, 0, stream>>>(S, Abf);
    dgemm<<<NTILES * 8, 1024, 0, stream>>>(Abf, kvTf, out);
}

// Round 16
// 36.148 us; speedup vs baseline: 1.2347x; 1.0754x over previous
//
#include <hip/hip_runtime.h>
#include <math.h>

constexpr int D  = 768;
constexpr int NQ = 8;
constexpr int B  = 32;
constexpr int NP = 196;      // n_patch
constexpr int KT = 7;        // K tiles of 32
constexpr int KP = KT * 32;  // 224 padded K
constexpr int TPAD = 776;    // LDS tile row stride (shorts)
constexpr int NTOFF = 28;    // off-diag 4x4-group tiles: C(8,2)
constexpr int NTILES = 32;   // + 4 diag-combo tiles (2 groups each)
constexpr float EPS = 1e-5f;
constexpr float INV_SQRT_D = 0.036084391824351615f;  // 1/sqrt(768)

typedef __attribute__((ext_vector_type(8))) short short8;
typedef __attribute__((ext_vector_type(4))) float f32x4;

__device__ __forceinline__ float wave_reduce_sum(float v) {
#pragma unroll
    for (int off = 32; off > 0; off >>= 1) v += __shfl_xor(v, off, 64);
    return v;
}
__device__ __forceinline__ float wave_reduce_max(float v) {
#pragma unroll
    for (int off = 32; off > 0; off >>= 1) v = fmaxf(v, __shfl_xor(v, off, 64));
    return v;
}

__device__ __forceinline__ unsigned short f2bf(float x) {
    union { float f; unsigned u; } c; c.f = x;
    unsigned r = c.u + 0x7fffu + ((c.u >> 16) & 1u);   // RNE
    return (unsigned short)(r >> 16);
}

// Fused: LN(q)->qbf LDS + LN(kv 16-row half-tile) + MFMA scores S + frag pack.
// kvTf[b][dt:48][kt:7][slot:64][e:8], value = kvn[kt*32+kg*8+e][dt*16+dl].
// One block per (b, h), h in [0,14): rows [h*16, h*16+16).
__global__ __launch_bounds__(256, 4) void kv_fused(const float* __restrict__ q_x,
                                                   const float* __restrict__ qw,
                                                   const float* __restrict__ qb,
                                                   const float* __restrict__ kv_x,
                                                   const float* __restrict__ kw,
                                                   const float* __restrict__ kb,
                                                   float* __restrict__ S,
                                                   unsigned short* __restrict__ kvTf) {
    const int b = blockIdx.x / 14;
    const int h = blockIdx.x % 14;
    const int kt = h >> 1;
    const int kgbase = (h & 1) * 2;
    const int tid = threadIdx.x, wave = tid >> 6, lane = tid & 63;
    __shared__ unsigned short tile[16][TPAD];  // 24.8 KB
    __shared__ unsigned short qbf[8][TPAD];    // 12.4 KB

    const bool live = (h * 16) < NP;

    float wv[12], bv[12];
#pragma unroll
    for (int c = 0; c < 12; ++c) { wv[c] = kw[lane + 64 * c]; bv[c] = kb[lane + 64 * c]; }

    // q-LN -> qbf (bf16), distributed: wave w handles q rows {2w, 2w+1}
    if (live && wave < 4) {
        float wq[12], bq[12];
#pragma unroll
        for (int c = 0; c < 12; ++c) { wq[c] = qw[lane + 64 * c]; bq[c] = qb[lane + 64 * c]; }
        for (int rr = 0; rr < 2; ++rr) {
            const int q = wave * 2 + rr;
            float v[12];
            float s = 0.f;
#pragma unroll
            for (int c = 0; c < 12; ++c) { v[c] = q_x[q * D + lane + 64 * c]; s += v[c]; }
            s = wave_reduce_sum(s);
            const float mean = s * (1.0f / D);
            float ss = 0.f;
#pragma unroll
            for (int c = 0; c < 12; ++c) { v[c] -= mean; ss += v[c] * v[c]; }
            ss = wave_reduce_sum(ss);
            const float rs = rsqrtf(ss * (1.0f / D) + EPS);
#pragma unroll
            for (int c = 0; c < 12; ++c)
                qbf[q][lane + 64 * c] = f2bf(v[c] * rs * wq[c] + bq[c]);
        }
    }

    // kv-LN -> tile (bf16)
    for (int r = 0; r < 4; ++r) {
        const int nl = wave * 4 + r;
        const int n  = h * 16 + nl;
        if (n < NP) {
            const float* xr = kv_x + ((size_t)b * NP + n) * D;
            float v[12];
            float s = 0.f;
#pragma unroll
            for (int c = 0; c < 12; ++c) { v[c] = xr[lane + 64 * c]; s += v[c]; }
            s = wave_reduce_sum(s);
            const float mean = s * (1.0f / D);
            float ss = 0.f;
#pragma unroll
            for (int c = 0; c < 12; ++c) { v[c] -= mean; ss += v[c] * v[c]; }
            ss = wave_reduce_sum(ss);
            const float rs = rsqrtf(ss * (1.0f / D) + EPS);
#pragma unroll
            for (int c = 0; c < 12; ++c)
                tile[nl][lane + 64 * c] = f2bf(v[c] * rs * wv[c] + bv[c]);
        } else {
#pragma unroll
            for (int c = 0; c < 12; ++c) tile[nl][lane + 64 * c] = 0;
        }
    }
    __syncthreads();

    // frag-layout store: 48 dt * 32 local slots = 1536 chunks of 16B, 6/thread.
#pragma unroll
    for (int rep = 0; rep < 6; ++rep) {
        const int chunk = rep * 256 + tid;
        const int dt = chunk >> 5, ls = chunk & 31;
        const int hi = ls >> 4, dl = ls & 15;
        const int kg = kgbase + hi;
        short8 vals;
#pragma unroll
        for (int e = 0; e < 8; ++e)
            vals[e] = (short)tile[hi * 8 + e][dt * 16 + dl];
        *(short8*)(kvTf + ((((size_t)b * 48 + dt) * KT + kt) * 64 + kg * 16 + dl) * 8) = vals;
    }

    // scores via MFMA: S16x8 = tile(16 x 768) x qbf^T, wave 0 only.
    // B-col q: cols 8-15 alias 0-7 (discarded). C: col=lane&15, row=(lane>>4)*4+reg.
    if (live && wave == 0) {
        f32x4 s0 = {0.f, 0.f, 0.f, 0.f}, s1 = {0.f, 0.f, 0.f, 0.f};
        const int ar = lane & 15, akg = lane >> 4;
        const int qr = ar & 7;
#pragma unroll
        for (int k2 = 0; k2 < 24; k2 += 2) {
            s0 = __builtin_amdgcn_mfma_f32_16x16x32_bf16(
                *(const short8*)&tile[ar][k2 * 32 + akg * 8],
                *(const short8*)&qbf[qr][k2 * 32 + akg * 8], s0, 0, 0, 0);
            s1 = __builtin_amdgcn_mfma_f32_16x16x32_bf16(
                *(const short8*)&tile[ar][(k2 + 1) * 32 + akg * 8],
                *(const short8*)&qbf[qr][(k2 + 1) * 32 + akg * 8], s1, 0, 0, 0);
        }
        s0 = s0 + s1;
        const int q = lane & 15;
        if (q < NQ) {
#pragma unroll
            for (int reg = 0; reg < 4; ++reg) {
                const int n = h * 16 + akg * 4 + reg;
                if (n < NP) S[((size_t)b * NQ + q) * NP + n] = s0[reg] * INV_SQRT_D;
            }
        }
    }
}

// Softmax once per unordered pair u={i<j}: 16 rows r = dir*8+q
// (dir0 = softmax(S_i - S_j), dir1 = softmax(S_j - S_i)), written bf16 in
// MFMA-frag layout Abf[u][kt:7][slot:64][e:8], slot = kg*16 + r.
__global__ __launch_bounds__(512) void aprep(const float* __restrict__ S,
                                             unsigned short* __restrict__ Abf) {
    const int u = blockIdx.x;
    int uu = u, i = 0;
    while (uu >= 31 - i) { uu -= 31 - i; ++i; }
    const int j = i + 1 + uu;

    const int tid = threadIdx.x, wave = tid >> 6, lane = tid & 63;
    __shared__ unsigned short lrow[16][KP];  // 7 KB

    for (int jj = 0; jj < 2; ++jj) {
        const int r = wave * 2 + jj;          // 0..15
        const int dir = r >> 3, q = r & 7;
        const float* Sa = S + ((size_t)(dir ? j : i) * NQ + q) * NP;
        const float* Sb = S + ((size_t)(dir ? i : j) * NQ + q) * NP;
        float v[4];
        float m = -1e30f;
#pragma unroll
        for (int c = 0; c < 4; ++c) {
            const int n = lane + 64 * c;
            v[c] = (n < NP) ? (Sa[n] - Sb[n]) : -1e30f;
            m = fmaxf(m, v[c]);
        }
        m = wave_reduce_max(m);
        float e[4];
        float sum = 0.f;
#pragma unroll
        for (int c = 0; c < 4; ++c) {
            const int n = lane + 64 * c;
            e[c] = (n < NP) ? __expf(v[c] - m) : 0.f;
            sum += e[c];
        }
        sum = wave_reduce_sum(sum);
        const float rinv = 1.0f / sum;
#pragma unroll
        for (int c = 0; c < 4; ++c) {
            const int n = lane + 64 * c;
            if (n < KP) lrow[r][n] = (n < NP) ? f2bf(e[c] * rinv) : (unsigned short)0;
        }
    }
    __syncthreads();

    if (tid < 448) {
        const int kt = tid >> 6, slot = tid & 63;
        const int kg = slot >> 4, lr = slot & 15;
        const short8 vals = *(const short8*)(&lrow[lr][kt * 32 + kg * 8]);
        *(short8*)(Abf + (((size_t)u * KT + kt) * 64 + slot) * 8) = vals;
    }
}

// dgemm v4: 8-wave (512 thr) LDS-staged pair GEMM, 48 KB LDS -> 2 blocks/CU
// so one block's MFMA phase overlaps the other's staging drain.
// Block = (tile t, cs of 16): 48-col slice (3 dt). 8 waves.
//  t < 28 (off-diag, groups gi<gj): wave = (pi, bh): pairs (i=4gi+pi,
//    j=4gj+2bh) and (i, j+1), all 3 dt. Shared ki read: 9 reads/12 MFMAs.
//  t >= 28 (diag-combo): waves 0-5: 2 pairs each from the two 4-group
//    6-enums; waves 6,7 zero-fill the 8 diagonal outputs.
// acc = A@kv_i + (-A)@kv_j; rows dir0 -> out[i*B+j], dir1 -> -acc at [j*B+i].
__global__ __launch_bounds__(512, 4) void dgemm(const unsigned short* __restrict__ Abf,
                                                const unsigned short* __restrict__ kvTf,
                                                float* __restrict__ out) {
    const int bid = blockIdx.x;
    const int t = bid >> 4, cs = bid & 15;   // XCD = bid%8 = cs%8
    const int tid = threadIdx.x, wave = tid >> 6, lane = tid & 63;

    __shared__ unsigned short stg[2][8][3][64][8];  // 48 KB double-buffered

    const bool offd = (t < NTOFF);
    int gi = 0, gj = 0;
    if (offd) {
        int tt = t, a = 0;
        while (tt >= 7 - a) { tt -= 7 - a; ++a; }
        gi = a; gj = a + 1 + tt;
    }
    const int dbase = 8 * (t - NTOFF);

    // ---- wave decode: 2 pairs, all 3 dt ----
    int i0 = 0, j0 = 0, i1 = 0, j1 = 0;
    int p0i = 0, p0j = 0, p1i = 0, p1j = 0;
    bool compute = true;
    if (offd) {
        const int pi = wave >> 1, bh = wave & 1;
        i0 = 4 * gi + pi; j0 = 4 * gj + 2 * bh;
        i1 = i0;          j1 = j0 + 1;
        p0i = pi; p0j = 4 + 2 * bh; p1i = pi; p1j = p0j + 1;
    } else if (wave < 6) {
        const int g = wave / 3, k3 = wave - 3 * g;
        const int ea[6] = {0, 0, 0, 1, 1, 2}, eb[6] = {1, 2, 3, 2, 3, 3};
        const int e0 = 2 * k3, e1 = e0 + 1;
        p0i = 4 * g + ea[e0]; p0j = 4 * g + eb[e0];
        p1i = 4 * g + ea[e1]; p1j = 4 * g + eb[e1];
        i0 = dbase + p0i; j0 = dbase + p0j;
        i1 = dbase + p1i; j1 = dbase + p1j;
    } else {
        compute = false;
        const int zw = wave - 6;
#pragma unroll
        for (int t2 = 0; t2 < 4; ++t2) {
            const int ii = dbase + zw * 4 + t2;
            float* base = out + (size_t)(ii * B + ii) * NQ * D + cs * 48;
#pragma unroll
            for (int rep = 0; rep < 6; ++rep) {
                const int e = rep * 64 + lane;
                const int q = e / 48, c = e - q * 48;
                base[q * D + c] = 0.f;
            }
        }
    }

    // ---- A prefetch to registers (2 pairs x 7 KB) ----
    short8 areg0[KT], areg1[KT];
    if (compute) {
        const int u0 = (i0 * (63 - i0)) / 2 + (j0 - i0 - 1);
        const int u1 = (i1 * (63 - i1)) / 2 + (j1 - i1 - 1);
        const unsigned short* Au0 = Abf + (size_t)u0 * KT * 512 + (size_t)lane * 8;
        const unsigned short* Au1 = Abf + (size_t)u1 * KT * 512 + (size_t)lane * 8;
#pragma unroll
        for (int kt = 0; kt < KT; ++kt) {
            areg0[kt] = *(const short8*)(Au0 + (size_t)kt * 512);
            areg1[kt] = *(const short8*)(Au1 + (size_t)kt * 512);
        }
    }

    // ---- staging: wave stages panel sp = wave, dt 0..2 ----
    const int sp = wave;
    const int sb = offd ? ((sp < 4) ? (4 * gi + sp) : (4 * gj + sp - 4)) : (dbase + sp);
    const unsigned short* gbase =
        kvTf + (((size_t)sb * 48 + cs * 3) * KT) * 512 + (size_t)lane * 8;

    f32x4 acc0[3], acc1[3];
#pragma unroll
    for (int nf = 0; nf < 3; ++nf) {
        f32x4 z = {0.f, 0.f, 0.f, 0.f};
        acc0[nf] = z; acc1[nf] = z;
    }

#pragma unroll
    for (int r = 0; r < 3; ++r)
        __builtin_amdgcn_global_load_lds(
            (const __attribute__((address_space(1))) void*)(gbase + ((size_t)r * KT) * 512),
            (__attribute__((address_space(3))) void*)(&stg[0][sp][r][0][0]), 16, 0, 0);
    __syncthreads();

    int buf = 0;
    for (int kt = 0; kt < KT; ++kt) {
        if (kt + 1 < KT) {
#pragma unroll
            for (int r = 0; r < 3; ++r)
                __builtin_amdgcn_global_load_lds(
                    (const __attribute__((address_space(1))) void*)(gbase + ((size_t)r * KT + kt + 1) * 512),
                    (__attribute__((address_space(3))) void*)(&stg[buf ^ 1][sp][r][0][0]), 16, 0, 0);
        }
        if (compute) {
            const short8 a0 = areg0[kt], a1 = areg1[kt];
            short8 na0, na1;
#pragma unroll
            for (int e = 0; e < 8; ++e) {
                na0[e] = (short)(a0[e] ^ (short)0x8000);
                na1[e] = (short)(a1[e] ^ (short)0x8000);
            }
            if (offd) {  // shared ki: 9 ds_reads feed 12 MFMAs
#pragma unroll
                for (int nf = 0; nf < 3; ++nf) {
                    const short8 ki  = *(const short8*)(&stg[buf][p0i][nf][lane][0]);
                    const short8 kj0 = *(const short8*)(&stg[buf][p0j][nf][lane][0]);
                    const short8 kj1 = *(const short8*)(&stg[buf][p1j][nf][lane][0]);
                    acc0[nf] = __builtin_amdgcn_mfma_f32_16x16x32_bf16(a0,  ki,  acc0[nf], 0, 0, 0);
                    acc0[nf] = __builtin_amdgcn_mfma_f32_16x16x32_bf16(na0, kj0, acc0[nf], 0, 0, 0);
                    acc1[nf] = __builtin_amdgcn_mfma_f32_16x16x32_bf16(a1,  ki,  acc1[nf], 0, 0, 0);
                    acc1[nf] = __builtin_amdgcn_mfma_f32_16x16x32_bf16(na1, kj1, acc1[nf], 0, 0, 0);
                }
            } else {
#pragma unroll
                for (int nf = 0; nf < 3; ++nf) {
                    const short8 k0i = *(const short8*)(&stg[buf][p0i][nf][lane][0]);
                    const short8 k0j = *(const short8*)(&stg[buf][p0j][nf][lane][0]);
                    const short8 k1i = *(const short8*)(&stg[buf][p1i][nf][lane][0]);
                    const short8 k1j = *(const short8*)(&stg[buf][p1j][nf][lane][0]);
                    acc0[nf] = __builtin_amdgcn_mfma_f32_16x16x32_bf16(a0,  k0i, acc0[nf], 0, 0, 0);
                    acc0[nf] = __builtin_amdgcn_mfma_f32_16x16x32_bf16(na0, k0j, acc0[nf], 0, 0, 0);
                    acc1[nf] = __builtin_amdgcn_mfma_f32_16x16x32_bf16(a1,  k1i, acc1[nf], 0, 0, 0);
                    acc1[nf] = __builtin_amdgcn_mfma_f32_16x16x32_bf16(na1, k1j, acc1[nf], 0, 0, 0);
                }
            }
        }
        __syncthreads();
        buf ^= 1;
    }

    // ---- epilogue: C row-in-tile = (lane>>4)*4 + reg, col = lane&15 ----
    if (compute) {
        const int kgrp = lane >> 4, dl = lane & 15;
        const int colb = cs * 48 + dl;
#pragma unroll
        for (int pr = 0; pr < 2; ++pr) {
            const int i = pr ? i1 : i0, j = pr ? j1 : j0;
            const f32x4* acc = pr ? acc1 : acc0;
            const int pij = i * B + j, pji = j * B + i;
#pragma unroll
            for (int reg = 0; reg < 4; ++reg) {
                const int r = kgrp * 4 + reg;
                const int dirr = r >> 3, qq = r & 7;
                const int p = dirr ? pji : pij;
                const float sgn = dirr ? -1.f : 1.f;
                float* op = out + ((size_t)p * NQ + qq) * D + colb;
#pragma unroll
                for (int nf = 0; nf < 3; ++nf) op[nf * 16] = sgn * acc[nf][reg];
            }
        }
    }
}

extern "C" void kernel_launch(void* const* d_in, const int* in_sizes, int n_in,
                              void* d_out, int out_size, void* d_ws, size_t ws_size,
                              hipStream_t stream) {
    const float* q_x     = (const float*)d_in[0];
    const float* kv_x    = (const float*)d_in[1];
    const float* ln_q_w  = (const float*)d_in[2];
    const float* ln_q_b  = (const float*)d_in[3];
    const float* ln_kv_w = (const float*)d_in[4];
    const float* ln_kv_b = (const float*)d_in[5];
    float* out = (float*)d_out;

    float* ws = (float*)d_ws;
    float* S  = ws;                                             // 32*8*196 f32
    unsigned short* kvTf = (unsigned short*)(ws + B * NQ * NP);  // 32*48*7*512 bf16
    unsigned short* Abf  = kvTf + (size_t)B * 48 * KT * 512;     // 496*7*512 bf16

    kv_fused<<<B * 14, 256, 0, stream>>>(q_x, ln_q_w, ln_q_b, kv_x, ln_kv_w, ln_kv_b, S, kvTf);
    aprep<<<(B * (B - 1)) / 2, 512, 0, stream>>>(S, Abf);
    dgemm<<<NTILES * 16, 512, 0, stream>>>(Abf, kvTf, out);
}

// Round 17
// 35.771 us; speedup vs baseline: 1.2477x; 1.0105x over previous
//
#include <hip/hip_runtime.h>
#include <math.h>

constexpr int D  = 768;
constexpr int NQ = 8;
constexpr int B  = 32;
constexpr int NP = 196;      // n_patch
constexpr int KT = 7;        // K tiles of 32
constexpr int KP = KT * 32;  // 224 padded K
constexpr int TPAD = 776;    // LDS tile row stride (shorts)
constexpr int NTOFF = 28;    // off-diag 4x4-group tiles: C(8,2)
constexpr int NTILES = 32;   // + 4 diag-combo tiles (2 groups each)
constexpr float EPS = 1e-5f;
constexpr float INV_SQRT_D = 0.036084391824351615f;  // 1/sqrt(768)

typedef __attribute__((ext_vector_type(8))) short short8;
typedef __attribute__((ext_vector_type(4))) float f32x4;

__device__ __forceinline__ float wave_reduce_sum(float v) {
#pragma unroll
    for (int off = 32; off > 0; off >>= 1) v += __shfl_xor(v, off, 64);
    return v;
}
__device__ __forceinline__ float wave_reduce_max(float v) {
#pragma unroll
    for (int off = 32; off > 0; off >>= 1) v = fmaxf(v, __shfl_xor(v, off, 64));
    return v;
}

__device__ __forceinline__ unsigned short f2bf(float x) {
    union { float f; unsigned u; } c; c.f = x;
    unsigned r = c.u + 0x7fffu + ((c.u >> 16) & 1u);   // RNE
    return (unsigned short)(r >> 16);
}

// Fused: LN(q)->qbf LDS + LN(kv 16-row half-tile) + MFMA scores S + frag pack.
// kvTf[b][dt:48][kt:7][slot:64][e:8], value = kvn[kt*32+kg*8+e][dt*16+dl].
// One block per (b, h), h in [0,14): rows [h*16, h*16+16).
// Frag pack is DIRECT from registers: wave w holds rows 4w..4w+3, which is
// exactly the e-halfchunk (kg = kgbase+(w>>1), e = 4*(w&1)+r) -> uint2 store.
__global__ __launch_bounds__(256, 4) void kv_fused(const float* __restrict__ q_x,
                                                   const float* __restrict__ qw,
                                                   const float* __restrict__ qb,
                                                   const float* __restrict__ kv_x,
                                                   const float* __restrict__ kw,
                                                   const float* __restrict__ kb,
                                                   float* __restrict__ S,
                                                   unsigned short* __restrict__ kvTf) {
    const int b = blockIdx.x / 14;
    const int h = blockIdx.x % 14;
    const int kt = h >> 1;
    const int kgbase = (h & 1) * 2;
    const int tid = threadIdx.x, wave = tid >> 6, lane = tid & 63;
    __shared__ unsigned short tile[16][TPAD];  // 24.8 KB (scores A-source)
    __shared__ unsigned short qbf[8][TPAD];    // 12.4 KB

    const bool live = (h * 16) < NP;

    float wv[12], bv[12];
#pragma unroll
    for (int c = 0; c < 12; ++c) { wv[c] = kw[lane + 64 * c]; bv[c] = kb[lane + 64 * c]; }

    // q-LN -> qbf (bf16), distributed: wave w handles q rows {2w, 2w+1}
    if (live && wave < 4) {
        float wq[12], bq[12];
#pragma unroll
        for (int c = 0; c < 12; ++c) { wq[c] = qw[lane + 64 * c]; bq[c] = qb[lane + 64 * c]; }
        for (int rr = 0; rr < 2; ++rr) {
            const int q = wave * 2 + rr;
            float v[12];
            float s = 0.f;
#pragma unroll
            for (int c = 0; c < 12; ++c) { v[c] = q_x[q * D + lane + 64 * c]; s += v[c]; }
            s = wave_reduce_sum(s);
            const float mean = s * (1.0f / D);
            float ss = 0.f;
#pragma unroll
            for (int c = 0; c < 12; ++c) { v[c] -= mean; ss += v[c] * v[c]; }
            ss = wave_reduce_sum(ss);
            const float rs = rsqrtf(ss * (1.0f / D) + EPS);
#pragma unroll
            for (int c = 0; c < 12; ++c)
                qbf[q][lane + 64 * c] = f2bf(v[c] * rs * wq[c] + bq[c]);
        }
    }

    // kv-LN -> tile (bf16) + register pack pk01/pk23 (rows 4w..4w+3, col d)
    unsigned pk01[12], pk23[12];
#pragma unroll
    for (int r = 0; r < 4; ++r) {
        const int nl = wave * 4 + r;
        const int n  = h * 16 + nl;
        if (n < NP) {
            const float* xr = kv_x + ((size_t)b * NP + n) * D;
            float v[12];
            float s = 0.f;
#pragma unroll
            for (int c = 0; c < 12; ++c) { v[c] = xr[lane + 64 * c]; s += v[c]; }
            s = wave_reduce_sum(s);
            const float mean = s * (1.0f / D);
            float ss = 0.f;
#pragma unroll
            for (int c = 0; c < 12; ++c) { v[c] -= mean; ss += v[c] * v[c]; }
            ss = wave_reduce_sum(ss);
            const float rs = rsqrtf(ss * (1.0f / D) + EPS);
#pragma unroll
            for (int c = 0; c < 12; ++c) {
                const unsigned short bf = f2bf(v[c] * rs * wv[c] + bv[c]);
                tile[nl][lane + 64 * c] = bf;
                if (r == 0)      pk01[c] = bf;
                else if (r == 1) pk01[c] |= ((unsigned)bf << 16);
                else if (r == 2) pk23[c] = bf;
                else             pk23[c] |= ((unsigned)bf << 16);
            }
        } else {
#pragma unroll
            for (int c = 0; c < 12; ++c) {
                tile[nl][lane + 64 * c] = 0;
                if (r == 0)      pk01[c] = 0;
                else if (r == 1) pk01[c] &= 0xffffu;
                else if (r == 2) pk23[c] = 0;
                else             pk23[c] &= 0xffffu;
            }
        }
    }

    // direct frag store: 12 x 8B per thread, no LDS gather
    {
        const int kg = kgbase + (wave >> 1);
        const int eh = (wave & 1);
        const int dl = lane & 15;
#pragma unroll
        for (int c = 0; c < 12; ++c) {
            const int dt = (lane >> 4) + 4 * c;
            uint2 val; val.x = pk01[c]; val.y = pk23[c];
            *(uint2*)(kvTf + ((((size_t)b * 48 + dt) * KT + kt) * 64 + kg * 16 + dl) * 8 + eh * 4) = val;
        }
    }
    __syncthreads();

    // scores via MFMA: S16x8 = tile(16 x 768) x qbf^T, wave 0 only.
    // B-col q: cols 8-15 alias 0-7 (discarded). C: col=lane&15, row=(lane>>4)*4+reg.
    if (live && wave == 0) {
        f32x4 s0 = {0.f, 0.f, 0.f, 0.f}, s1 = {0.f, 0.f, 0.f, 0.f};
        const int ar = lane & 15, akg = lane >> 4;
        const int qr = ar & 7;
#pragma unroll
        for (int k2 = 0; k2 < 24; k2 += 2) {
            s0 = __builtin_amdgcn_mfma_f32_16x16x32_bf16(
                *(const short8*)&tile[ar][k2 * 32 + akg * 8],
                *(const short8*)&qbf[qr][k2 * 32 + akg * 8], s0, 0, 0, 0);
            s1 = __builtin_amdgcn_mfma_f32_16x16x32_bf16(
                *(const short8*)&tile[ar][(k2 + 1) * 32 + akg * 8],
                *(const short8*)&qbf[qr][(k2 + 1) * 32 + akg * 8], s1, 0, 0, 0);
        }
        s0 = s0 + s1;
        const int q = lane & 15;
        if (q < NQ) {
#pragma unroll
            for (int reg = 0; reg < 4; ++reg) {
                const int n = h * 16 + akg * 4 + reg;
                if (n < NP) S[((size_t)b * NQ + q) * NP + n] = s0[reg] * INV_SQRT_D;
            }
        }
    }
}

// Softmax once per unordered pair u={i<j}: 16 rows r = dir*8+q
// (dir0 = softmax(S_i - S_j), dir1 = softmax(S_j - S_i)), written bf16 in
// MFMA-frag layout Abf[u][kt:7][slot:64][e:8], slot = kg*16 + r.
__global__ __launch_bounds__(512) void aprep(const float* __restrict__ S,
                                             unsigned short* __restrict__ Abf) {
    const int u = blockIdx.x;
    int uu = u, i = 0;
    while (uu >= 31 - i) { uu -= 31 - i; ++i; }
    const int j = i + 1 + uu;

    const int tid = threadIdx.x, wave = tid >> 6, lane = tid & 63;
    __shared__ unsigned short lrow[16][KP];  // 7 KB

    for (int jj = 0; jj < 2; ++jj) {
        const int r = wave * 2 + jj;          // 0..15
        const int dir = r >> 3, q = r & 7;
        const float* Sa = S + ((size_t)(dir ? j : i) * NQ + q) * NP;
        const float* Sb = S + ((size_t)(dir ? i : j) * NQ + q) * NP;
        float v[4];
        float m = -1e30f;
#pragma unroll
        for (int c = 0; c < 4; ++c) {
            const int n = lane + 64 * c;
            v[c] = (n < NP) ? (Sa[n] - Sb[n]) : -1e30f;
            m = fmaxf(m, v[c]);
        }
        m = wave_reduce_max(m);
        float e[4];
        float sum = 0.f;
#pragma unroll
        for (int c = 0; c < 4; ++c) {
            const int n = lane + 64 * c;
            e[c] = (n < NP) ? __expf(v[c] - m) : 0.f;
            sum += e[c];
        }
        sum = wave_reduce_sum(sum);
        const float rinv = 1.0f / sum;
#pragma unroll
        for (int c = 0; c < 4; ++c) {
            const int n = lane + 64 * c;
            if (n < KP) lrow[r][n] = (n < NP) ? f2bf(e[c] * rinv) : (unsigned short)0;
        }
    }
    __syncthreads();

    if (tid < 448) {
        const int kt = tid >> 6, slot = tid & 63;
        const int kg = slot >> 4, lr = slot & 15;
        const short8 vals = *(const short8*)(&lrow[lr][kt * 32 + kg * 8]);
        *(short8*)(Abf + (((size_t)u * KT + kt) * 64 + slot) * 8) = vals;
    }
}

// dgemm v4: 8-wave (512 thr) LDS-staged pair GEMM, 48 KB LDS -> 2 blocks/CU
// so one block's MFMA phase overlaps the other's staging drain.
// Block = (tile t, cs of 16): 48-col slice (3 dt). 8 waves.
//  t < 28 (off-diag, groups gi<gj): wave = (pi, bh): pairs (i=4gi+pi,
//    j=4gj+2bh) and (i, j+1), all 3 dt. Shared ki read: 9 reads/12 MFMAs.
//  t >= 28 (diag-combo): waves 0-5: 2 pairs each from the two 4-group
//    6-enums; waves 6,7 zero-fill the 8 diagonal outputs.
// acc = A@kv_i + (-A)@kv_j; rows dir0 -> out[i*B+j], dir1 -> -acc at [j*B+i].
__global__ __launch_bounds__(512, 4) void dgemm(const unsigned short* __restrict__ Abf,
                                                const unsigned short* __restrict__ kvTf,
                                                float* __restrict__ out) {
    const int bid = blockIdx.x;
    const int t = bid >> 4, cs = bid & 15;   // XCD = bid%8 = cs%8
    const int tid = threadIdx.x, wave = tid >> 6, lane = tid & 63;

    __shared__ unsigned short stg[2][8][3][64][8];  // 48 KB double-buffered

    const bool offd = (t < NTOFF);
    int gi = 0, gj = 0;
    if (offd) {
        int tt = t, a = 0;
        while (tt >= 7 - a) { tt -= 7 - a; ++a; }
        gi = a; gj = a + 1 + tt;
    }
    const int dbase = 8 * (t - NTOFF);

    // ---- wave decode: 2 pairs, all 3 dt ----
    int i0 = 0, j0 = 0, i1 = 0, j1 = 0;
    int p0i = 0, p0j = 0, p1i = 0, p1j = 0;
    bool compute = true;
    if (offd) {
        const int pi = wave >> 1, bh = wave & 1;
        i0 = 4 * gi + pi; j0 = 4 * gj + 2 * bh;
        i1 = i0;          j1 = j0 + 1;
        p0i = pi; p0j = 4 + 2 * bh; p1i = pi; p1j = p0j + 1;
    } else if (wave < 6) {
        const int g = wave / 3, k3 = wave - 3 * g;
        const int ea[6] = {0, 0, 0, 1, 1, 2}, eb[6] = {1, 2, 3, 2, 3, 3};
        const int e0 = 2 * k3, e1 = e0 + 1;
        p0i = 4 * g + ea[e0]; p0j = 4 * g + eb[e0];
        p1i = 4 * g + ea[e1]; p1j = 4 * g + eb[e1];
        i0 = dbase + p0i; j0 = dbase + p0j;
        i1 = dbase + p1i; j1 = dbase + p1j;
    } else {
        compute = false;
        const int zw = wave - 6;
#pragma unroll
        for (int t2 = 0; t2 < 4; ++t2) {
            const int ii = dbase + zw * 4 + t2;
            float* base = out + (size_t)(ii * B + ii) * NQ * D + cs * 48;
#pragma unroll
            for (int rep = 0; rep < 6; ++rep) {
                const int e = rep * 64 + lane;
                const int q = e / 48, c = e - q * 48;
                base[q * D + c] = 0.f;
            }
        }
    }

    // ---- A prefetch to registers (2 pairs x 7 KB) ----
    short8 areg0[KT], areg1[KT];
    if (compute) {
        const int u0 = (i0 * (63 - i0)) / 2 + (j0 - i0 - 1);
        const int u1 = (i1 * (63 - i1)) / 2 + (j1 - i1 - 1);
        const unsigned short* Au0 = Abf + (size_t)u0 * KT * 512 + (size_t)lane * 8;
        const unsigned short* Au1 = Abf + (size_t)u1 * KT * 512 + (size_t)lane * 8;
#pragma unroll
        for (int kt = 0; kt < KT; ++kt) {
            areg0[kt] = *(const short8*)(Au0 + (size_t)kt * 512);
            areg1[kt] = *(const short8*)(Au1 + (size_t)kt * 512);
        }
    }

    // ---- staging: wave stages panel sp = wave, dt 0..2 ----
    const int sp = wave;
    const int sb = offd ? ((sp < 4) ? (4 * gi + sp) : (4 * gj + sp - 4)) : (dbase + sp);
    const unsigned short* gbase =
        kvTf + (((size_t)sb * 48 + cs * 3) * KT) * 512 + (size_t)lane * 8;

    f32x4 acc0[3], acc1[3];
#pragma unroll
    for (int nf = 0; nf < 3; ++nf) {
        f32x4 z = {0.f, 0.f, 0.f, 0.f};
        acc0[nf] = z; acc1[nf] = z;
    }

#pragma unroll
    for (int r = 0; r < 3; ++r)
        __builtin_amdgcn_global_load_lds(
            (const __attribute__((address_space(1))) void*)(gbase + ((size_t)r * KT) * 512),
            (__attribute__((address_space(3))) void*)(&stg[0][sp][r][0][0]), 16, 0, 0);
    __syncthreads();

    int buf = 0;
    for (int kt = 0; kt < KT; ++kt) {
        if (kt + 1 < KT) {
#pragma unroll
            for (int r = 0; r < 3; ++r)
                __builtin_amdgcn_global_load_lds(
                    (const __attribute__((address_space(1))) void*)(gbase + ((size_t)r * KT + kt + 1) * 512),
                    (__attribute__((address_space(3))) void*)(&stg[buf ^ 1][sp][r][0][0]), 16, 0, 0);
        }
        if (compute) {
            const short8 a0 = areg0[kt], a1 = areg1[kt];
            short8 na0, na1;
#pragma unroll
            for (int e = 0; e < 8; ++e) {
                na0[e] = (short)(a0[e] ^ (short)0x8000);
                na1[e] = (short)(a1[e] ^ (short)0x8000);
            }
            if (offd) {  // shared ki: 9 ds_reads feed 12 MFMAs
#pragma unroll
                for (int nf = 0; nf < 3; ++nf) {
                    const short8 ki  = *(const short8*)(&stg[buf][p0i][nf][lane][0]);
                    const short8 kj0 = *(const short8*)(&stg[buf][p0j][nf][lane][0]);
                    const short8 kj1 = *(const short8*)(&stg[buf][p1j][nf][lane][0]);
                    acc0[nf] = __builtin_amdgcn_mfma_f32_16x16x32_bf16(a0,  ki,  acc0[nf], 0, 0, 0);
                    acc0[nf] = __builtin_amdgcn_mfma_f32_16x16x32_bf16(na0, kj0, acc0[nf], 0, 0, 0);
                    acc1[nf] = __builtin_amdgcn_mfma_f32_16x16x32_bf16(a1,  ki,  acc1[nf], 0, 0, 0);
                    acc1[nf] = __builtin_amdgcn_mfma_f32_16x16x32_bf16(na1, kj1, acc1[nf], 0, 0, 0);
                }
            } else {
#pragma unroll
                for (int nf = 0; nf < 3; ++nf) {
                    const short8 k0i = *(const short8*)(&stg[buf][p0i][nf][lane][0]);
                    const short8 k0j = *(const short8*)(&stg[buf][p0j][nf][lane][0]);
                    const short8 k1i = *(const short8*)(&stg[buf][p1i][nf][lane][0]);
                    const short8 k1j = *(const short8*)(&stg[buf][p1j][nf][lane][0]);
                    acc0[nf] = __builtin_amdgcn_mfma_f32_16x16x32_bf16(a0,  k0i, acc0[nf], 0, 0, 0);
                    acc0[nf] = __builtin_amdgcn_mfma_f32_16x16x32_bf16(na0, k0j, acc0[nf], 0, 0, 0);
                    acc1[nf] = __builtin_amdgcn_mfma_f32_16x16x32_bf16(a1,  k1i, acc1[nf], 0, 0, 0);
                    acc1[nf] = __builtin_amdgcn_mfma_f32_16x16x32_bf16(na1, k1j, acc1[nf], 0, 0, 0);
                }
            }
        }
        __syncthreads();
        buf ^= 1;
    }

    // ---- epilogue: C row-in-tile = (lane>>4)*4 + reg, col = lane&15 ----
    if (compute) {
        const int kgrp = lane >> 4, dl = lane & 15;
        const int colb = cs * 48 + dl;
#pragma unroll
        for (int pr = 0; pr < 2; ++pr) {
            const int i = pr ? i1 : i0, j = pr ? j1 : j0;
            const f32x4* acc = pr ? acc1 : acc0;
            const int pij = i * B + j, pji = j * B + i;
#pragma unroll
            for (int reg = 0; reg < 4; ++reg) {
                const int r = kgrp * 4 + reg;
                const int dirr = r >> 3, qq = r & 7;
                const int p = dirr ? pji : pij;
                const float sgn = dirr ? -1.f : 1.f;
                float* op = out + ((size_t)p * NQ + qq) * D + colb;
#pragma unroll
                for (int nf = 0; nf < 3; ++nf) op[nf * 16] = sgn * acc[nf][reg];
            }
        }
    }
}

extern "C" void kernel_launch(void* const* d_in, const int* in_sizes, int n_in,
                              void* d_out, int out_size, void* d_ws, size_t ws_size,
                              hipStream_t stream) {
    const float* q_x     = (const float*)d_in[0];
    const float* kv_x    = (const float*)d_in[1];
    const float* ln_q_w  = (const float*)d_in[2];
    const float* ln_q_b  = (const float*)d_in[3];
    const float* ln_kv_w = (const float*)d_in[4];
    const float* ln_kv_b = (const float*)d_in[5];
    float* out = (float*)d_out;

    float* ws = (float*)d_ws;
    float* S  = ws;                                             // 32*8*196 f32
    unsigned short* kvTf = (unsigned short*)(ws + B * NQ * NP);  // 32*48*7*512 bf16
    unsigned short* Abf  = kvTf + (size_t)B * 48 * KT * 512;     // 496*7*512 bf16

    kv_fused<<<B * 14, 256, 0, stream>>>(q_x, ln_q_w, ln_q_b, kv_x, ln_kv_w, ln_kv_b, S, kvTf);
    aprep<<<(B * (B - 1)) / 2, 512, 0, stream>>>(S, Abf);
    dgemm<<<NTILES * 16, 512, 0, stream>>>(Abf, kvTf, out);
}

// Round 18
// 35.724 us; speedup vs baseline: 1.2493x; 1.0013x over previous
//
#include <hip/hip_runtime.h>
#include <math.h>

constexpr int D  = 768;
constexpr int NQ = 8;
constexpr int B  = 32;
constexpr int NP = 196;      // n_patch
constexpr int KT = 7;        // K tiles of 32
constexpr int KP = KT * 32;  // 224 padded K
constexpr int TPAD = 776;    // LDS tile row stride (shorts)
constexpr int NTOFF = 28;    // off-diag 4x4-group tiles: C(8,2)
constexpr int NTILES = 32;   // + 4 diag-combo tiles (2 groups each)
constexpr float EPS = 1e-5f;
constexpr float INV_SQRT_D = 0.036084391824351615f;  // 1/sqrt(768)

typedef __attribute__((ext_vector_type(8))) short short8;
typedef __attribute__((ext_vector_type(4))) float f32x4;

__device__ __forceinline__ float wave_reduce_sum(float v) {
#pragma unroll
    for (int off = 32; off > 0; off >>= 1) v += __shfl_xor(v, off, 64);
    return v;
}
__device__ __forceinline__ float wave_reduce_max(float v) {
#pragma unroll
    for (int off = 32; off > 0; off >>= 1) v = fmaxf(v, __shfl_xor(v, off, 64));
    return v;
}

__device__ __forceinline__ unsigned short f2bf(float x) {
    union { float f; unsigned u; } c; c.f = x;
    unsigned r = c.u + 0x7fffu + ((c.u >> 16) & 1u);   // RNE
    return (unsigned short)(r >> 16);
}

// Fused: LN(q)->qbf LDS + LN(kv 16-row half-tile) + MFMA scores S + frag pack.
// kvTf[b][dt:48][kt:7][slot:64][e:8], value = kvn[kt*32+kg*8+e][dt*16+dl].
// One block per (b, h), h in [0,14): rows [h*16, h*16+16).
// LN uses single-pass moments (sum, sumsq; var = E[x^2]-mu^2) with 2-row
// batching -> 4 independent shfl chains interleaved (ILP), halving the
// serial cross-lane latency twice.
__global__ __launch_bounds__(256, 4) void kv_fused(const float* __restrict__ q_x,
                                                   const float* __restrict__ qw,
                                                   const float* __restrict__ qb,
                                                   const float* __restrict__ kv_x,
                                                   const float* __restrict__ kw,
                                                   const float* __restrict__ kb,
                                                   float* __restrict__ S,
                                                   unsigned short* __restrict__ kvTf) {
    const int b = blockIdx.x / 14;
    const int h = blockIdx.x % 14;
    const int kt = h >> 1;
    const int kgbase = (h & 1) * 2;
    const int tid = threadIdx.x, wave = tid >> 6, lane = tid & 63;
    __shared__ unsigned short tile[16][TPAD];  // 24.8 KB (scores A-source)
    __shared__ unsigned short qbf[8][TPAD];    // 12.4 KB

    const bool live = (h * 16) < NP;

    float wv[12], bv[12];
#pragma unroll
    for (int c = 0; c < 12; ++c) { wv[c] = kw[lane + 64 * c]; bv[c] = kb[lane + 64 * c]; }

    // q-LN -> qbf (bf16): wave w handles q rows {2w, 2w+1}, batched.
    if (live && wave < 4) {
        float wq[12], bq[12];
#pragma unroll
        for (int c = 0; c < 12; ++c) { wq[c] = qw[lane + 64 * c]; bq[c] = qb[lane + 64 * c]; }
        float v0[12], v1[12];
        float s0 = 0.f, t0 = 0.f, s1 = 0.f, t1 = 0.f;
        const int q0 = wave * 2, q1 = q0 + 1;
#pragma unroll
        for (int c = 0; c < 12; ++c) {
            v0[c] = q_x[q0 * D + lane + 64 * c];
            v1[c] = q_x[q1 * D + lane + 64 * c];
            s0 += v0[c]; t0 = fmaf(v0[c], v0[c], t0);
            s1 += v1[c]; t1 = fmaf(v1[c], v1[c], t1);
        }
#pragma unroll
        for (int off = 32; off > 0; off >>= 1) {
            s0 += __shfl_xor(s0, off, 64);
            s1 += __shfl_xor(s1, off, 64);
            t0 += __shfl_xor(t0, off, 64);
            t1 += __shfl_xor(t1, off, 64);
        }
        const float m0 = s0 * (1.0f / D), m1 = s1 * (1.0f / D);
        const float r0 = rsqrtf(t0 * (1.0f / D) - m0 * m0 + EPS);
        const float r1 = rsqrtf(t1 * (1.0f / D) - m1 * m1 + EPS);
#pragma unroll
        for (int c = 0; c < 12; ++c) {
            qbf[q0][lane + 64 * c] = f2bf((v0[c] - m0) * r0 * wq[c] + bq[c]);
            qbf[q1][lane + 64 * c] = f2bf((v1[c] - m1) * r1 * wq[c] + bq[c]);
        }
    }

    // kv-LN -> tile (bf16) + register pack, rows 4w..4w+3 in 2 batches of 2.
    unsigned pk01[12], pk23[12];
#pragma unroll
    for (int b2 = 0; b2 < 2; ++b2) {
        const int nl0 = wave * 4 + 2 * b2;
        const int n0 = h * 16 + nl0, n1 = n0 + 1;
        const bool a0 = n0 < NP, a1 = n1 < NP;
        const float* x0 = kv_x + ((size_t)b * NP + n0) * D;
        const float* x1 = kv_x + ((size_t)b * NP + n1) * D;
        float v0[12], v1[12];
        float s0 = 0.f, t0 = 0.f, s1 = 0.f, t1 = 0.f;
#pragma unroll
        for (int c = 0; c < 12; ++c) {
            v0[c] = a0 ? x0[lane + 64 * c] : 0.f;
            v1[c] = a1 ? x1[lane + 64 * c] : 0.f;
            s0 += v0[c]; t0 = fmaf(v0[c], v0[c], t0);
            s1 += v1[c]; t1 = fmaf(v1[c], v1[c], t1);
        }
#pragma unroll
        for (int off = 32; off > 0; off >>= 1) {
            s0 += __shfl_xor(s0, off, 64);
            s1 += __shfl_xor(s1, off, 64);
            t0 += __shfl_xor(t0, off, 64);
            t1 += __shfl_xor(t1, off, 64);
        }
        const float m0 = s0 * (1.0f / D), m1 = s1 * (1.0f / D);
        const float r0 = rsqrtf(t0 * (1.0f / D) - m0 * m0 + EPS);
        const float r1 = rsqrtf(t1 * (1.0f / D) - m1 * m1 + EPS);
#pragma unroll
        for (int c = 0; c < 12; ++c) {
            const int d = lane + 64 * c;
            const unsigned short bf0 = a0 ? f2bf((v0[c] - m0) * r0 * wv[c] + bv[c]) : (unsigned short)0;
            const unsigned short bf1 = a1 ? f2bf((v1[c] - m1) * r1 * wv[c] + bv[c]) : (unsigned short)0;
            tile[nl0][d] = bf0;
            tile[nl0 + 1][d] = bf1;
            const unsigned packed = (unsigned)bf0 | ((unsigned)bf1 << 16);
            if (b2 == 0) pk01[c] = packed; else pk23[c] = packed;
        }
    }

    // direct frag store: 12 x 8B per thread, no LDS gather
    {
        const int kg = kgbase + (wave >> 1);
        const int eh = (wave & 1);
        const int dl = lane & 15;
#pragma unroll
        for (int c = 0; c < 12; ++c) {
            const int dt = (lane >> 4) + 4 * c;
            uint2 val; val.x = pk01[c]; val.y = pk23[c];
            *(uint2*)(kvTf + ((((size_t)b * 48 + dt) * KT + kt) * 64 + kg * 16 + dl) * 8 + eh * 4) = val;
        }
    }
    __syncthreads();

    // scores via MFMA: S16x8 = tile(16 x 768) x qbf^T, wave 0 only.
    // B-col q: cols 8-15 alias 0-7 (discarded). C: col=lane&15, row=(lane>>4)*4+reg.
    if (live && wave == 0) {
        f32x4 s0 = {0.f, 0.f, 0.f, 0.f}, s1 = {0.f, 0.f, 0.f, 0.f};
        const int ar = lane & 15, akg = lane >> 4;
        const int qr = ar & 7;
#pragma unroll
        for (int k2 = 0; k2 < 24; k2 += 2) {
            s0 = __builtin_amdgcn_mfma_f32_16x16x32_bf16(
                *(const short8*)&tile[ar][k2 * 32 + akg * 8],
                *(const short8*)&qbf[qr][k2 * 32 + akg * 8], s0, 0, 0, 0);
            s1 = __builtin_amdgcn_mfma_f32_16x16x32_bf16(
                *(const short8*)&tile[ar][(k2 + 1) * 32 + akg * 8],
                *(const short8*)&qbf[qr][(k2 + 1) * 32 + akg * 8], s1, 0, 0, 0);
        }
        s0 = s0 + s1;
        const int q = lane & 15;
        if (q < NQ) {
#pragma unroll
            for (int reg = 0; reg < 4; ++reg) {
                const int n = h * 16 + akg * 4 + reg;
                if (n < NP) S[((size_t)b * NQ + q) * NP + n] = s0[reg] * INV_SQRT_D;
            }
        }
    }
}

// Softmax once per unordered pair u={i<j}: 16 rows r = dir*8+q
// (dir0 = softmax(S_i - S_j), dir1 = softmax(S_j - S_i)), written bf16 in
// MFMA-frag layout Abf[u][kt:7][slot:64][e:8], slot = kg*16 + r.
__global__ __launch_bounds__(512) void aprep(const float* __restrict__ S,
                                             unsigned short* __restrict__ Abf) {
    const int u = blockIdx.x;
    int uu = u, i = 0;
    while (uu >= 31 - i) { uu -= 31 - i; ++i; }
    const int j = i + 1 + uu;

    const int tid = threadIdx.x, wave = tid >> 6, lane = tid & 63;
    __shared__ unsigned short lrow[16][KP];  // 7 KB

    for (int jj = 0; jj < 2; ++jj) {
        const int r = wave * 2 + jj;          // 0..15
        const int dir = r >> 3, q = r & 7;
        const float* Sa = S + ((size_t)(dir ? j : i) * NQ + q) * NP;
        const float* Sb = S + ((size_t)(dir ? i : j) * NQ + q) * NP;
        float v[4];
        float m = -1e30f;
#pragma unroll
        for (int c = 0; c < 4; ++c) {
            const int n = lane + 64 * c;
            v[c] = (n < NP) ? (Sa[n] - Sb[n]) : -1e30f;
            m = fmaxf(m, v[c]);
        }
        m = wave_reduce_max(m);
        float e[4];
        float sum = 0.f;
#pragma unroll
        for (int c = 0; c < 4; ++c) {
            const int n = lane + 64 * c;
            e[c] = (n < NP) ? __expf(v[c] - m) : 0.f;
            sum += e[c];
        }
        sum = wave_reduce_sum(sum);
        const float rinv = 1.0f / sum;
#pragma unroll
        for (int c = 0; c < 4; ++c) {
            const int n = lane + 64 * c;
            if (n < KP) lrow[r][n] = (n < NP) ? f2bf(e[c] * rinv) : (unsigned short)0;
        }
    }
    __syncthreads();

    if (tid < 448) {
        const int kt = tid >> 6, slot = tid & 63;
        const int kg = slot >> 4, lr = slot & 15;
        const short8 vals = *(const short8*)(&lrow[lr][kt * 32 + kg * 8]);
        *(short8*)(Abf + (((size_t)u * KT + kt) * 64 + slot) * 8) = vals;
    }
}

// dgemm v4: 8-wave (512 thr) LDS-staged pair GEMM, 48 KB LDS -> 2 blocks/CU
// so one block's MFMA phase overlaps the other's staging drain.
// Block = (tile t, cs of 16): 48-col slice (3 dt). 8 waves.
//  t < 28 (off-diag, groups gi<gj): wave = (pi, bh): pairs (i=4gi+pi,
//    j=4gj+2bh) and (i, j+1), all 3 dt. Shared ki read: 9 reads/12 MFMAs.
//  t >= 28 (diag-combo): waves 0-5: 2 pairs each from the two 4-group
//    6-enums; waves 6,7 zero-fill the 8 diagonal outputs.
// acc = A@kv_i + (-A)@kv_j; rows dir0 -> out[i*B+j], dir1 -> -acc at [j*B+i].
__global__ __launch_bounds__(512, 4) void dgemm(const unsigned short* __restrict__ Abf,
                                                const unsigned short* __restrict__ kvTf,
                                                float* __restrict__ out) {
    const int bid = blockIdx.x;
    const int t = bid >> 4, cs = bid & 15;   // XCD = bid%8 = cs%8
    const int tid = threadIdx.x, wave = tid >> 6, lane = tid & 63;

    __shared__ unsigned short stg[2][8][3][64][8];  // 48 KB double-buffered

    const bool offd = (t < NTOFF);
    int gi = 0, gj = 0;
    if (offd) {
        int tt = t, a = 0;
        while (tt >= 7 - a) { tt -= 7 - a; ++a; }
        gi = a; gj = a + 1 + tt;
    }
    const int dbase = 8 * (t - NTOFF);

    // ---- wave decode: 2 pairs, all 3 dt ----
    int i0 = 0, j0 = 0, i1 = 0, j1 = 0;
    int p0i = 0, p0j = 0, p1i = 0, p1j = 0;
    bool compute = true;
    if (offd) {
        const int pi = wave >> 1, bh = wave & 1;
        i0 = 4 * gi + pi; j0 = 4 * gj + 2 * bh;
        i1 = i0;          j1 = j0 + 1;
        p0i = pi; p0j = 4 + 2 * bh; p1i = pi; p1j = p0j + 1;
    } else if (wave < 6) {
        const int g = wave / 3, k3 = wave - 3 * g;
        const int ea[6] = {0, 0, 0, 1, 1, 2}, eb[6] = {1, 2, 3, 2, 3, 3};
        const int e0 = 2 * k3, e1 = e0 + 1;
        p0i = 4 * g + ea[e0]; p0j = 4 * g + eb[e0];
        p1i = 4 * g + ea[e1]; p1j = 4 * g + eb[e1];
        i0 = dbase + p0i; j0 = dbase + p0j;
        i1 = dbase + p1i; j1 = dbase + p1j;
    } else {
        compute = false;
        const int zw = wave - 6;
#pragma unroll
        for (int t2 = 0; t2 < 4; ++t2) {
            const int ii = dbase + zw * 4 + t2;
            float* base = out + (size_t)(ii * B + ii) * NQ * D + cs * 48;
#pragma unroll
            for (int rep = 0; rep < 6; ++rep) {
                const int e = rep * 64 + lane;
                const int q = e / 48, c = e - q * 48;
                base[q * D + c] = 0.f;
            }
        }
    }

    // ---- A prefetch to registers (2 pairs x 7 KB) ----
    short8 areg0[KT], areg1[KT];
    if (compute) {
        const int u0 = (i0 * (63 - i0)) / 2 + (j0 - i0 - 1);
        const int u1 = (i1 * (63 - i1)) / 2 + (j1 - i1 - 1);
        const unsigned short* Au0 = Abf + (size_t)u0 * KT * 512 + (size_t)lane * 8;
        const unsigned short* Au1 = Abf + (size_t)u1 * KT * 512 + (size_t)lane * 8;
#pragma unroll
        for (int kt = 0; kt < KT; ++kt) {
            areg0[kt] = *(const short8*)(Au0 + (size_t)kt * 512);
            areg1[kt] = *(const short8*)(Au1 + (size_t)kt * 512);
        }
    }

    // ---- staging: wave stages panel sp = wave, dt 0..2 ----
    const int sp = wave;
    const int sb = offd ? ((sp < 4) ? (4 * gi + sp) : (4 * gj + sp - 4)) : (dbase + sp);
    const unsigned short* gbase =
        kvTf + (((size_t)sb * 48 + cs * 3) * KT) * 512 + (size_t)lane * 8;

    f32x4 acc0[3], acc1[3];
#pragma unroll
    for (int nf = 0; nf < 3; ++nf) {
        f32x4 z = {0.f, 0.f, 0.f, 0.f};
        acc0[nf] = z; acc1[nf] = z;
    }

#pragma unroll
    for (int r = 0; r < 3; ++r)
        __builtin_amdgcn_global_load_lds(
            (const __attribute__((address_space(1))) void*)(gbase + ((size_t)r * KT) * 512),
            (__attribute__((address_space(3))) void*)(&stg[0][sp][r][0][0]), 16, 0, 0);
    __syncthreads();

    int buf = 0;
    for (int kt = 0; kt < KT; ++kt) {
        if (kt + 1 < KT) {
#pragma unroll
            for (int r = 0; r < 3; ++r)
                __builtin_amdgcn_global_load_lds(
                    (const __attribute__((address_space(1))) void*)(gbase + ((size_t)r * KT + kt + 1) * 512),
                    (__attribute__((address_space(3))) void*)(&stg[buf ^ 1][sp][r][0][0]), 16, 0, 0);
        }
        if (compute) {
            const short8 a0 = areg0[kt], a1 = areg1[kt];
            short8 na0, na1;
#pragma unroll
            for (int e = 0; e < 8; ++e) {
                na0[e] = (short)(a0[e] ^ (short)0x8000);
                na1[e] = (short)(a1[e] ^ (short)0x8000);
            }
            if (offd) {  // shared ki: 9 ds_reads feed 12 MFMAs
#pragma unroll
                for (int nf = 0; nf < 3; ++nf) {
                    const short8 ki  = *(const short8*)(&stg[buf][p0i][nf][lane][0]);
                    const short8 kj0 = *(const short8*)(&stg[buf][p0j][nf][lane][0]);
                    const short8 kj1 = *(const short8*)(&stg[buf][p1j][nf][lane][0]);
                    acc0[nf] = __builtin_amdgcn_mfma_f32_16x16x32_bf16(a0,  ki,  acc0[nf], 0, 0, 0);
                    acc0[nf] = __builtin_amdgcn_mfma_f32_16x16x32_bf16(na0, kj0, acc0[nf], 0, 0, 0);
                    acc1[nf] = __builtin_amdgcn_mfma_f32_16x16x32_bf16(a1,  ki,  acc1[nf], 0, 0, 0);
                    acc1[nf] = __builtin_amdgcn_mfma_f32_16x16x32_bf16(na1, kj1, acc1[nf], 0, 0, 0);
                }
            } else {
#pragma unroll
                for (int nf = 0; nf < 3; ++nf) {
                    const short8 k0i = *(const short8*)(&stg[buf][p0i][nf][lane][0]);
                    const short8 k0j = *(const short8*)(&stg[buf][p0j][nf][lane][0]);
                    const short8 k1i = *(const short8*)(&stg[buf][p1i][nf][lane][0]);
                    const short8 k1j = *(const short8*)(&stg[buf][p1j][nf][lane][0]);
                    acc0[nf] = __builtin_amdgcn_mfma_f32_16x16x32_bf16(a0,  k0i, acc0[nf], 0, 0, 0);
                    acc0[nf] = __builtin_amdgcn_mfma_f32_16x16x32_bf16(na0, k0j, acc0[nf], 0, 0, 0);
                    acc1[nf] = __builtin_amdgcn_mfma_f32_16x16x32_bf16(a1,  k1i, acc1[nf], 0, 0, 0);
                    acc1[nf] = __builtin_amdgcn_mfma_f32_16x16x32_bf16(na1, k1j, acc1[nf], 0, 0, 0);
                }
            }
        }
        __syncthreads();
        buf ^= 1;
    }

    // ---- epilogue: C row-in-tile = (lane>>4)*4 + reg, col = lane&15 ----
    if (compute) {
        const int kgrp = lane >> 4, dl = lane & 15;
        const int colb = cs * 48 + dl;
#pragma unroll
        for (int pr = 0; pr < 2; ++pr) {
            const int i = pr ? i1 : i0, j = pr ? j1 : j0;
            const f32x4* acc = pr ? acc1 : acc0;
            const int pij = i * B + j, pji = j * B + i;
#pragma unroll
            for (int reg = 0; reg < 4; ++reg) {
                const int r = kgrp * 4 + reg;
                const int dirr = r >> 3, qq = r & 7;
                const int p = dirr ? pji : pij;
                const float sgn = dirr ? -1.f : 1.f;
                float* op = out + ((size_t)p * NQ + qq) * D + colb;
#pragma unroll
                for (int nf = 0; nf < 3; ++nf) op[nf * 16] = sgn * acc[nf][reg];
            }
        }
    }
}

extern "C" void kernel_launch(void* const* d_in, const int* in_sizes, int n_in,
                              void* d_out, int out_size, void* d_ws, size_t ws_size,
                              hipStream_t stream) {
    const float* q_x     = (const float*)d_in[0];
    const float* kv_x    = (const float*)d_in[1];
    const float* ln_q_w  = (const float*)d_in[2];
    const float* ln_q_b  = (const float*)d_in[3];
    const float* ln_kv_w = (const float*)d_in[4];
    const float* ln_kv_b = (const float*)d_in[5];
    float* out = (float*)d_out;

    float* ws = (float*)d_ws;
    float* S  = ws;                                             // 32*8*196 f32
    unsigned short* kvTf = (unsigned short*)(ws + B * NQ * NP);  // 32*48*7*512 bf16
    unsigned short* Abf  = kvTf + (size_t)B * 48 * KT * 512;     // 496*7*512 bf16

    kv_fused<<<B * 14, 256, 0, stream>>>(q_x, ln_q_w, ln_q_b, kv_x, ln_kv_w, ln_kv_b, S, kvTf);
    aprep<<<(B * (B - 1)) / 2, 512, 0, stream>>>(S, Abf);
    dgemm<<<NTILES * 16, 512, 0, stream>>>(Abf, kvTf, out);
}